// Round 2
// baseline (1689.359 us; speedup 1.0000x reference)
//
#include <hip/hip_runtime.h>
#include <cstdint>
#include <cstddef>

typedef unsigned short u16;
typedef __attribute__((ext_vector_type(8))) short bf16x8;   // 8 bf16 = 4 VGPR
typedef __attribute__((ext_vector_type(4))) float f32x4;

constexpr int KN = 100000;            // batch nodes
constexpr int ME = 600000;            // edges in block
constexpr int NB = (KN + 63) / 64;    // 1563 node-blocks of 64

static __device__ __forceinline__ float bf2f(u16 u) {
  union { unsigned int i; float f; } x; x.i = ((unsigned int)u) << 16; return x.f;
}
static __device__ __forceinline__ u16 f2bf(float f) {
  union { float f; unsigned int i; } x; x.f = f;
  unsigned int r = x.i + 0x7FFFu + ((x.i >> 16) & 1u);   // RNE
  return (u16)(r >> 16);
}

// ---------------- CSR build: count / scan / scatter ----------------

__global__ void k_count(const int* __restrict__ ei, int* __restrict__ cnt) {
  int m = blockIdx.x * blockDim.x + threadIdx.x;
  if (m < ME) atomicAdd(&cnt[ei[ME + m] >> 6], 1);
}

__global__ void k_scan(const int* __restrict__ cnt, int* __restrict__ row_start,
                       int* __restrict__ cursor, int n) {
  __shared__ int s[2048];
  const int t = threadIdx.x;
  s[t]        = (t < n)        ? cnt[t]        : 0;
  s[t + 1024] = (t + 1024 < n) ? cnt[t + 1024] : 0;
  __syncthreads();
  for (int off = 1; off < 2048; off <<= 1) {
    int v0 = (t >= off) ? s[t - off] : 0;
    int v1 = s[t + 1024 - off];
    __syncthreads();
    s[t] += v0;
    s[t + 1024] += v1;
    __syncthreads();
  }
  if (t == 0) row_start[0] = 0;
  for (int i = t; i < n; i += 1024) {
    row_start[i + 1] = s[i];
    cursor[i] = (i == 0) ? 0 : s[i - 1];
  }
}

__global__ void k_scatter(const int* __restrict__ ei, const int* __restrict__ e_id,
                          const int* __restrict__ n_id, const float* __restrict__ edge_t,
                          const float* __restrict__ last_update,
                          int* __restrict__ cursor, int4* __restrict__ packed) {
  int m = blockIdx.x * blockDim.x + threadIdx.x;
  if (m >= ME) return;
  int src = ei[m];
  int dst = ei[ME + m];
  int eid = e_id[m];
  float rel = edge_t[eid] - last_update[n_id[src]];
  int pos = atomicAdd(&cursor[dst >> 6], 1);
  packed[pos] = make_int4(src, eid, __float_as_int(rel), dst);
}

// ---------------- K1: node gather + {Wq,Wk,Wv,Wskip} projection ----------------
// block = 512 thr (8 waves). tile = 64 rows x 512 cols; wave w -> cols w*64..+63.

__global__ __launch_bounds__(512) void k_nodeproj(
    const int* __restrict__ n_id,
    const float* __restrict__ node_feat, const float* __restrict__ memory,
    const float* __restrict__ Wq, const float* __restrict__ bq,
    const float* __restrict__ Wk, const float* __restrict__ bk,
    const float* __restrict__ Wv, const float* __restrict__ bv,
    const float* __restrict__ Wskip, const float* __restrict__ bskip,
    u16* __restrict__ qo, u16* __restrict__ ko, u16* __restrict__ vo,
    float* __restrict__ z)
{
  __shared__ u16 a_lds[64][264];            // 64 rows x 256 (+8 pad) bf16
  const int i0  = blockIdx.x * 64;
  const int tid = threadIdx.x;
  const int wid = tid >> 6;
  const int lane = tid & 63;
  const int l16 = lane & 15;
  const int g4  = lane >> 4;

  // stage A: x = [memory || node_feat][n_id] -> bf16 LDS
  {
    const int r   = tid >> 3;               // 0..63
    const int qtr = tid & 7;                // 8 chunks of 32 cols
    const int row = i0 + r;
    const int nid = (row < KN) ? n_id[row] : 0;
    const float* srcp = (qtr < 4) ? (memory + (size_t)nid * 128 + qtr * 32)
                                  : (node_feat + (size_t)nid * 128 + (qtr - 4) * 32);
    #pragma unroll
    for (int j = 0; j < 4; ++j) {
      float4 f0 = ((const float4*)srcp)[2 * j];
      float4 f1 = ((const float4*)srcp)[2 * j + 1];
      bf16x8 t;
      t[0] = (short)f2bf(f0.x); t[1] = (short)f2bf(f0.y);
      t[2] = (short)f2bf(f0.z); t[3] = (short)f2bf(f0.w);
      t[4] = (short)f2bf(f1.x); t[5] = (short)f2bf(f1.y);
      t[6] = (short)f2bf(f1.z); t[7] = (short)f2bf(f1.w);
      *(bf16x8*)&a_lds[r][qtr * 32 + j * 8] = t;
    }
  }
  __syncthreads();

  const int c0 = wid * 64;                  // global col base, wave-uniform
  const int wm = c0 >> 7;                   // 0=q 1=k 2=v 3=skip (uniform)
  const float* W  = (wm == 0) ? Wq : (wm == 1) ? Wk : (wm == 2) ? Wv : Wskip;
  const float* bp = (wm == 0) ? bq : (wm == 1) ? bk : (wm == 2) ? bv : bskip;

  f32x4 acc[4][4];
  #pragma unroll
  for (int rf = 0; rf < 4; ++rf)
    #pragma unroll
    for (int nf = 0; nf < 4; ++nf)
      acc[rf][nf] = (f32x4){0.f, 0.f, 0.f, 0.f};

  // two B-phases (kc 0..3, 4..7) to cap VGPRs
  for (int kp = 0; kp < 2; ++kp) {
    bf16x8 Breg[4][4];
    #pragma unroll
    for (int kc = 0; kc < 4; ++kc) {
      const int kb = (kp * 4 + kc) * 32 + g4 * 8;
      #pragma unroll
      for (int nf = 0; nf < 4; ++nf) {
        const int cc = ((c0 & 127) + nf * 16 + l16);
        bf16x8 t;
        #pragma unroll
        for (int u = 0; u < 8; ++u) t[u] = (short)f2bf(W[(size_t)(kb + u) * 128 + cc]);
        Breg[kc][nf] = t;
      }
    }
    #pragma unroll
    for (int kc = 0; kc < 4; ++kc) {
      bf16x8 afr[4];
      #pragma unroll
      for (int rf = 0; rf < 4; ++rf)
        afr[rf] = *(const bf16x8*)&a_lds[rf * 16 + l16][(kp * 4 + kc) * 32 + g4 * 8];
      #pragma unroll
      for (int rf = 0; rf < 4; ++rf)
        #pragma unroll
        for (int nf = 0; nf < 4; ++nf)
          acc[rf][nf] = __builtin_amdgcn_mfma_f32_16x16x32_bf16(afr[rf], Breg[kc][nf], acc[rf][nf], 0, 0, 0);
    }
  }

  // epilogue: bias + store (q/k/v bf16, skip fp32 into d_out)
  #pragma unroll
  for (int nf = 0; nf < 4; ++nf) {
    const int cc = (c0 & 127) + nf * 16 + l16;
    const float bias = bp[cc];
    #pragma unroll
    for (int rf = 0; rf < 4; ++rf) {
      #pragma unroll
      for (int i = 0; i < 4; ++i) {
        const int row = i0 + rf * 16 + g4 * 4 + i;
        if (row < KN) {
          const float val = acc[rf][nf][i] + bias;
          const size_t off = (size_t)row * 128 + cc;
          if (wm == 0) qo[off] = f2bf(val);
          else if (wm == 1) ko[off] = f2bf(val);
          else if (wm == 2) vo[off] = f2bf(val);
          else z[off] = val;
        }
      }
    }
  }
}

// ---------------- K2: per-edge e-GEMM + attention + aggregation ----------------
// block = 512 thr (8 waves) owns 64 consecutive dst nodes; edges via CSR.
// wave wid: we=wid&3 -> edge group (16 edges), wn=wid>>2 -> head (64 cols).

__global__ __launch_bounds__(512) void k_edge(
    const int4* __restrict__ packed, const int* __restrict__ row_start,
    const float* __restrict__ edge_raw_msg,
    const float* __restrict__ w_t, const float* __restrict__ b_t,
    const float* __restrict__ We,
    const u16* __restrict__ qv, const u16* __restrict__ kv, const u16* __restrict__ vv,
    float* __restrict__ z)
{
  __shared__ float out_lds[64][128];
  __shared__ float denom_lds[64][2];
  __shared__ u16 attr_lds[64][264];         // [t_enc || msg] bf16, padded

  const int blk = blockIdx.x;
  const int i0  = blk * 64;
  const int tid = threadIdx.x;
  const int wid = tid >> 6;
  const int we  = wid & 3;
  const int wn  = wid >> 2;
  const int lane = tid & 63;
  const int l16 = lane & 15;
  const int g4  = lane >> 4;

  for (int idx = tid; idx < 64 * 128; idx += 512) ((float*)out_lds)[idx] = 0.f;
  if (tid < 128) ((float*)denom_lds)[tid] = 0.f;

  // full We (256x128) as per-wave B fragments in registers
  bf16x8 Breg[8][4];
  #pragma unroll
  for (int kc = 0; kc < 8; ++kc) {
    const int kb = kc * 32 + g4 * 8;
    #pragma unroll
    for (int nf = 0; nf < 4; ++nf) {
      const int c = wn * 64 + nf * 16 + l16;
      bf16x8 t;
      #pragma unroll
      for (int u = 0; u < 8; ++u) t[u] = (short)f2bf(We[(size_t)(kb + u) * 128 + c]);
      Breg[kc][nf] = t;
    }
  }
  __syncthreads();

  const int e0 = row_start[blk];
  const int e1 = row_start[blk + 1];
  const int eL  = tid >> 3;                 // staging: edge in tile
  const int sub = tid & 7;                  // staging: 16-col chunk

  for (int t0 = e0; t0 < e1; t0 += 64) {
    __syncthreads();                        // attr_lds reuse guard
    // ---- stage attr tile: cos(rel*w+b) cols 0..127, msg cols 128..255
    {
      const int eg = t0 + eL;
      const int4 m = (eg < e1) ? packed[eg] : make_int4(0, 0, 0, i0);
      const float rel = __int_as_float(m.z);
      bf16x8 cv0, cv1;
      #pragma unroll
      for (int u = 0; u < 8; ++u) {
        const int j = sub * 16 + u;
        cv0[u] = (short)f2bf(cosf(rel * w_t[j] + b_t[j]));
        cv1[u] = (short)f2bf(cosf(rel * w_t[j + 8] + b_t[j + 8]));
      }
      *(bf16x8*)&attr_lds[eL][sub * 16]     = cv0;
      *(bf16x8*)&attr_lds[eL][sub * 16 + 8] = cv1;
      const float4* mp = (const float4*)(edge_raw_msg + (size_t)m.y * 128 + sub * 16);
      float4 f0 = mp[0], f1 = mp[1], f2_ = mp[2], f3 = mp[3];
      bf16x8 mv0, mv1;
      mv0[0] = (short)f2bf(f0.x); mv0[1] = (short)f2bf(f0.y);
      mv0[2] = (short)f2bf(f0.z); mv0[3] = (short)f2bf(f0.w);
      mv0[4] = (short)f2bf(f1.x); mv0[5] = (short)f2bf(f1.y);
      mv0[6] = (short)f2bf(f1.z); mv0[7] = (short)f2bf(f1.w);
      mv1[0] = (short)f2bf(f2_.x); mv1[1] = (short)f2bf(f2_.y);
      mv1[2] = (short)f2bf(f2_.z); mv1[3] = (short)f2bf(f2_.w);
      mv1[4] = (short)f2bf(f3.x); mv1[5] = (short)f2bf(f3.y);
      mv1[6] = (short)f2bf(f3.z); mv1[7] = (short)f2bf(f3.w);
      *(bf16x8*)&attr_lds[eL][128 + sub * 16]     = mv0;
      *(bf16x8*)&attr_lds[eL][128 + sub * 16 + 8] = mv1;
    }
    __syncthreads();

    // ---- e-tile MFMA: [16 edges x 64 cols] per wave, K=256
    f32x4 acc[4];
    #pragma unroll
    for (int nf = 0; nf < 4; ++nf) acc[nf] = (f32x4){0.f, 0.f, 0.f, 0.f};
    #pragma unroll
    for (int kc = 0; kc < 8; ++kc) {
      const bf16x8 af = *(const bf16x8*)&attr_lds[we * 16 + l16][kc * 32 + g4 * 8];
      #pragma unroll
      for (int nf = 0; nf < 4; ++nf)
        acc[nf] = __builtin_amdgcn_mfma_f32_16x16x32_bf16(af, Breg[kc][nf], acc[nf], 0, 0, 0);
    }

    // ---- attention epilogue: 4 edges per lane (acc rows), head = wn
    #pragma unroll
    for (int i = 0; i < 4; ++i) {
      const int em = t0 + we * 16 + g4 * 4 + i;
      const bool valid = (em < e1);
      const int4 m = valid ? packed[em] : make_int4(0, 0, 0, i0);
      const int src = m.x;
      const int dl  = m.w - i0;
      float ef[4], vf[4];
      float pa = 0.f;
      #pragma unroll
      for (int nf = 0; nf < 4; ++nf) {
        const int c = wn * 64 + nf * 16 + l16;
        const float eg_ = acc[nf][i];
        const float kg = bf2f(kv[(size_t)src * 128 + c]);
        const float qg = bf2f(qv[(size_t)m.w * 128 + c]);
        vf[nf] = bf2f(vv[(size_t)src * 128 + c]);
        ef[nf] = eg_;
        pa += qg * (kg + eg_);
      }
      pa += __shfl_xor(pa, 1);
      pa += __shfl_xor(pa, 2);
      pa += __shfl_xor(pa, 4);
      pa += __shfl_xor(pa, 8);
      if (valid) {
        const float p = expf(pa * 0.125f);  // alpha = dot / sqrt(64)
        #pragma unroll
        for (int nf = 0; nf < 4; ++nf) {
          const int c = wn * 64 + nf * 16 + l16;
          atomicAdd(&out_lds[dl][c], p * (vf[nf] + ef[nf]));
        }
        if (l16 == 0) atomicAdd(&denom_lds[dl][wn], p);
      }
    }
  }
  __syncthreads();

  // ---- finalize: z = out/denom + skip (skip already in z)
  const int rem = (KN - i0 < 64) ? (KN - i0) : 64;
  const int li = tid >> 3;
  const int cb = (tid & 7) * 16;
  if (li < rem) {
    const float dh = denom_lds[li][cb >> 6];
    const float inv = (dh > 0.f) ? 1.f / dh : 0.f;
    const size_t off = (size_t)(i0 + li) * 128 + cb;
    #pragma unroll
    for (int j = 0; j < 4; ++j) {
      float4 zv = ((const float4*)(z + off))[j];
      zv.x += out_lds[li][cb + j * 4 + 0] * inv;
      zv.y += out_lds[li][cb + j * 4 + 1] * inv;
      zv.z += out_lds[li][cb + j * 4 + 2] * inv;
      zv.w += out_lds[li][cb + j * 4 + 3] * inv;
      ((float4*)(z + off))[j] = zv;
    }
  }
}

// ---------------- launch ----------------

extern "C" void kernel_launch(void* const* d_in, const int* in_sizes, int n_in,
                              void* d_out, int out_size, void* d_ws, size_t ws_size,
                              hipStream_t stream) {
  const int* n_id        = (const int*)d_in[0];
  const int* ei          = (const int*)d_in[1];
  const int* e_id        = (const int*)d_in[2];
  // d_in[3] t_targets unused by reference
  const float* node_feat = (const float*)d_in[4];
  const float* edge_msg  = (const float*)d_in[5];
  const float* edge_t    = (const float*)d_in[6];
  const float* memory_   = (const float*)d_in[7];
  const float* last_upd  = (const float*)d_in[8];
  const float* w_t       = (const float*)d_in[9];
  const float* b_t       = (const float*)d_in[10];
  const float* Wq = (const float*)d_in[11]; const float* bq = (const float*)d_in[12];
  const float* Wk = (const float*)d_in[13]; const float* bk = (const float*)d_in[14];
  const float* Wv = (const float*)d_in[15]; const float* bv = (const float*)d_in[16];
  const float* We = (const float*)d_in[17];
  const float* Wskip = (const float*)d_in[18]; const float* bskip = (const float*)d_in[19];
  float* z = (float*)d_out;

  char* ws = (char*)d_ws;
  u16* q = (u16*)ws;            ws += (size_t)KN * 128 * 2;
  u16* k = (u16*)ws;            ws += (size_t)KN * 128 * 2;
  u16* v = (u16*)ws;            ws += (size_t)KN * 128 * 2;
  int4* packed = (int4*)ws;     ws += (size_t)ME * 16;
  int* cnt = (int*)ws;          ws += (size_t)NB * 4;
  int* row_start = (int*)ws;    ws += (size_t)(NB + 1) * 4;
  int* cursor = (int*)ws;       ws += (size_t)NB * 4;

  hipMemsetAsync(cnt, 0, (size_t)NB * 4, stream);
  k_count<<<(ME + 255) / 256, 256, 0, stream>>>(ei, cnt);
  k_scan<<<1, 1024, 0, stream>>>(cnt, row_start, cursor, NB);
  k_scatter<<<(ME + 255) / 256, 256, 0, stream>>>(ei, e_id, n_id, edge_t, last_upd, cursor, packed);
  k_nodeproj<<<NB, 512, 0, stream>>>(n_id, node_feat, memory_,
                                     Wq, bq, Wk, bk, Wv, bv, Wskip, bskip,
                                     q, k, v, z);
  k_edge<<<NB, 512, 0, stream>>>(packed, row_start, edge_msg, w_t, b_t, We,
                                 q, k, v, z);
}